// Round 11
// baseline (37.685 us; speedup 1.0000x reference)
//
#include <hip/hip_runtime.h>
#include <math.h>

// Batched 8-qubit state-vector sim. fp32 in / fp32 out.
// Base: R10 (PASSED, 35.7us). This round: 64-lane-per-element layout for 2x
// occupancy (8 waves/SIMD). One element per wave64; grid 2048 blocks.
//   amplitude index a = L*4 + r, L = lane (6 bits), r in [0,4) (2 reg bits)
//   wire w -> bit p = 7-w: p<=1 register bit, p>=2 lane bit (p-2)
// Exchange: masks 1,2 DPP quad_perm; 4,8,16 ds_swizzle; 32 __shfl_xor (all
// individually validated R8/R10).
// NOTE: popcount-fused RZ(phi) is FORBIDDEN - reproducibly wrong (R1/R7/R9,
// exact err 8.789e-2); explicit per-wire RZ only.

constexpr int NREG = 4;

template<int MASK>
__device__ __forceinline__ float lxor(float x) {
  if constexpr (MASK == 32) {
    return __shfl_xor(x, 32, 64);
  } else {
    int xi = __float_as_int(x);
    int r;
    if constexpr (MASK == 1)      r = __builtin_amdgcn_mov_dpp(xi, 0xB1, 0xF, 0xF, true); // quad_perm [1,0,3,2]
    else if constexpr (MASK == 2) r = __builtin_amdgcn_mov_dpp(xi, 0x4E, 0xF, 0xF, true); // quad_perm [2,3,0,1]
    else                          r = __builtin_amdgcn_ds_swizzle(xi, (MASK << 10) | 0x1F); // xor within 32 lanes
    return __int_as_float(r);
  }
}

struct State {
  float re[NREG];
  float im[NREG];
};

// RY(theta): [[c,-s],[s,c]] on bit position P
template<int P>
__device__ __forceinline__ void ry_gate(State& st, float c, float s, int L) {
  if constexpr (P <= 1) {
    constexpr int m = 1 << P;
    #pragma unroll
    for (int r0 = 0; r0 < NREG; ++r0) {
      if (r0 & m) continue;
      const int r1 = r0 | m;
      float a0r = st.re[r0], a0i = st.im[r0];
      float a1r = st.re[r1], a1i = st.im[r1];
      st.re[r0] = fmaf(-s, a1r, c * a0r);
      st.im[r0] = fmaf(-s, a1i, c * a0i);
      st.re[r1] = fmaf( s, a0r, c * a1r);
      st.im[r1] = fmaf( s, a0i, c * a1i);
    }
  } else {
    constexpr int m = 1 << (P - 2);
    float ss = ((L >> (P - 2)) & 1) ? s : -s;
    #pragma unroll
    for (int r = 0; r < NREG; ++r) {
      float br = lxor<m>(st.re[r]);
      float bi = lxor<m>(st.im[r]);
      st.re[r] = fmaf(ss, br, c * st.re[r]);
      st.im[r] = fmaf(ss, bi, c * st.im[r]);
    }
  }
}

// RZ(t): diag(e^{-it/2}, e^{+it/2}); cz=cos(t/2), sz=sin(t/2)
template<int P>
__device__ __forceinline__ void rz_gate(State& st, float cz, float sz, int L) {
  if constexpr (P <= 1) {
    #pragma unroll
    for (int r = 0; r < NREG; ++r) {
      float sgn = ((r >> P) & 1) ? sz : -sz;
      float ar = st.re[r], ai = st.im[r];
      st.re[r] = fmaf(-sgn, ai, cz * ar);
      st.im[r] = fmaf( sgn, ar, cz * ai);
    }
  } else {
    float sgn = ((L >> (P - 2)) & 1) ? sz : -sz;
    #pragma unroll
    for (int r = 0; r < NREG; ++r) {
      float ar = st.re[r], ai = st.im[r];
      st.re[r] = fmaf(-sgn, ai, cz * ar);
      st.im[r] = fmaf( sgn, ar, cz * ai);
    }
  }
}

template<int PC, int PT>
__device__ __forceinline__ void cnot_gate(State& st, int L) {
  if constexpr (PT <= 1) {
    constexpr int mt = 1 << PT;
    if constexpr (PC <= 1) {
      constexpr int mc = 1 << PC;
      #pragma unroll
      for (int r0 = 0; r0 < NREG; ++r0) {
        if (!(r0 & mc) || (r0 & mt)) continue;
        const int r1 = r0 | mt;
        float t;
        t = st.re[r0]; st.re[r0] = st.re[r1]; st.re[r1] = t;
        t = st.im[r0]; st.im[r0] = st.im[r1]; st.im[r1] = t;
      }
    } else {
      bool cb = (L >> (PC - 2)) & 1;
      #pragma unroll
      for (int r0 = 0; r0 < NREG; ++r0) {
        if (r0 & mt) continue;
        const int r1 = r0 | mt;
        float a0r = st.re[r0], a1r = st.re[r1];
        float a0i = st.im[r0], a1i = st.im[r1];
        st.re[r0] = cb ? a1r : a0r;
        st.re[r1] = cb ? a0r : a1r;
        st.im[r0] = cb ? a1i : a0i;
        st.im[r1] = cb ? a0i : a1i;
      }
    }
  } else {
    constexpr int mt = 1 << (PT - 2);
    if constexpr (PC <= 1) {
      constexpr int mc = 1 << PC;
      #pragma unroll
      for (int r = 0; r < NREG; ++r) {
        if (!(r & mc)) continue;
        st.re[r] = lxor<mt>(st.re[r]);
        st.im[r] = lxor<mt>(st.im[r]);
      }
    } else {
      bool cb = (L >> (PC - 2)) & 1;
      #pragma unroll
      for (int r = 0; r < NREG; ++r) {
        float br = lxor<mt>(st.re[r]);
        float bi = lxor<mt>(st.im[r]);
        st.re[r] = cb ? br : st.re[r];
        st.im[r] = cb ? bi : st.im[r];
      }
    }
  }
}

// general complex 2x2 gate; u = {00r,00i,01r,01i,10r,10i,11r,11i} (LDS)
template<int P>
__device__ __forceinline__ void u3_gate(State& st, const float* u, int L) {
  float u00r=u[0],u00i=u[1],u01r=u[2],u01i=u[3],u10r=u[4],u10i=u[5],u11r=u[6],u11i=u[7];
  if constexpr (P <= 1) {
    constexpr int m = 1 << P;
    #pragma unroll
    for (int r0 = 0; r0 < NREG; ++r0) {
      if (r0 & m) continue;
      const int r1 = r0 | m;
      float a0r=st.re[r0], a0i=st.im[r0], a1r=st.re[r1], a1i=st.im[r1];
      st.re[r0] = u00r*a0r - u00i*a0i + u01r*a1r - u01i*a1i;
      st.im[r0] = u00r*a0i + u00i*a0r + u01r*a1i + u01i*a1r;
      st.re[r1] = u10r*a0r - u10i*a0i + u11r*a1r - u11i*a1i;
      st.im[r1] = u10r*a0i + u10i*a0r + u11r*a1i + u11i*a1r;
    }
  } else {
    constexpr int m = 1 << (P - 2);
    bool b = (L >> (P - 2)) & 1;
    float xr = b ? u11r : u00r, xi = b ? u11i : u00i;
    float yr = b ? u10r : u01r, yi = b ? u10i : u01i;
    #pragma unroll
    for (int r = 0; r < NREG; ++r) {
      float pr = lxor<m>(st.re[r]);
      float pi = lxor<m>(st.im[r]);
      float ar = st.re[r], ai = st.im[r];
      st.re[r] = xr*ar - xi*ai + yr*pr - yi*pi;
      st.im[r] = xr*ai + xi*ar + yr*pi + yi*pr;
    }
  }
}

// rz(hi); cnot(hi,lo); rz(lo); ry(hi); cnot(lo,hi); ry(hi); cnot(hi,lo); rz(lo)
template<int PH, int PL>
__device__ __forceinline__ void conv_block(State& st, int L,
    float crza,float srza, float crzb,float srzb, float crzc,float srzc,
    float crya,float srya, float cryb,float sryb) {
  rz_gate<PH>(st, crza, srza, L);
  cnot_gate<PH, PL>(st, L);
  rz_gate<PL>(st, crzb, srzb, L);
  ry_gate<PH>(st, crya, srya, L);
  cnot_gate<PL, PH>(st, L);
  ry_gate<PH>(st, cryb, sryb, L);
  cnot_gate<PH, PL>(st, L);
  rz_gate<PL>(st, crzc, srzc, L);
}

__global__ __launch_bounds__(256, 8) void qcnn_kernel(
    const float* __restrict__ theta, const float* __restrict__ phi,
    const float* __restrict__ rz_a, const float* __restrict__ ry_a,
    const float* __restrict__ u3_p,
    const float* __restrict__ w1, const float* __restrict__ b1,
    const float* __restrict__ w2, const float* __restrict__ b2,
    float* __restrict__ out, int B) {
  __shared__ float s_rz[21][2];   // (cos, sin) of half-angle
  __shared__ float s_ry[14][2];
  __shared__ float s_u3[6][8];
  __shared__ float s_w1[20];
  __shared__ float s_b1[10];
  __shared__ float s_w2[10];
  __shared__ float s_b2[1];

  const int tid = threadIdx.x;
  if (tid < 21) {
    float s, c; sincosf(0.5f * rz_a[tid], &s, &c);
    s_rz[tid][0] = c; s_rz[tid][1] = s;
  } else if (tid >= 32 && tid < 46) {
    int j = tid - 32;
    float s, c; sincosf(0.5f * ry_a[j], &s, &c);
    s_ry[j][0] = c; s_ry[j][1] = s;
  } else if (tid >= 64 && tid < 70) {
    int j = tid - 64;
    float t = u3_p[3*j], p = u3_p[3*j+1], l = u3_p[3*j+2];
    float st_, ct, sp, cp, sl, cl;
    sincosf(0.5f*t, &st_, &ct);
    sincosf(p, &sp, &cp);
    sincosf(l, &sl, &cl);
    s_u3[j][0] = ct;       s_u3[j][1] = 0.f;
    s_u3[j][2] = -cl*st_;  s_u3[j][3] = -sl*st_;
    s_u3[j][4] = cp*st_;   s_u3[j][5] = sp*st_;
    float eplr = cp*cl - sp*sl, epli = sp*cl + cp*sl;
    s_u3[j][6] = eplr*ct;  s_u3[j][7] = epli*ct;
  } else if (tid >= 96 && tid < 116) {
    s_w1[tid - 96] = w1[tid - 96];
  } else if (tid >= 128 && tid < 138) {
    s_b1[tid - 128] = b1[tid - 128];
  } else if (tid >= 160 && tid < 170) {
    s_w2[tid - 160] = w2[tid - 160];
  } else if (tid == 192) {
    s_b2[0] = b2[0];
  }
  __syncthreads();

  const int L = tid & 63;
  const int g = (blockIdx.x * blockDim.x + tid) >> 6;  // batch index (1 elem/wave)
  if (g < B) {
    float th = theta[g], ph = phi[g];
    float cth, sth; sincosf(0.5f*th, &sth, &cth);
    float cph, sph; sincosf(0.5f*ph, &sph, &cph);

    State st;
    #pragma unroll
    for (int r = 0; r < NREG; ++r) { st.re[r] = 0.f; st.im[r] = 0.f; }
    st.re[0] = (L == 0) ? 1.f : 0.f;

    #pragma unroll 1
    for (int cyc = 0; cyc < 4; ++cyc) {
      // RY(theta) on wires 0..7  (P = 7-w)
      ry_gate<7>(st, cth, sth, L);
      ry_gate<6>(st, cth, sth, L);
      ry_gate<5>(st, cth, sth, L);
      ry_gate<4>(st, cth, sth, L);
      ry_gate<3>(st, cth, sth, L);
      ry_gate<2>(st, cth, sth, L);
      ry_gate<1>(st, cth, sth, L);
      ry_gate<0>(st, cth, sth, L);
      // RZ(phi) on wires 0..7, explicit
      rz_gate<7>(st, cph, sph, L);
      rz_gate<6>(st, cph, sph, L);
      rz_gate<5>(st, cph, sph, L);
      rz_gate<4>(st, cph, sph, L);
      rz_gate<3>(st, cph, sph, L);
      rz_gate<2>(st, cph, sph, L);
      rz_gate<1>(st, cph, sph, L);
      rz_gate<0>(st, cph, sph, L);
      // CNOT ring (w, w+1)
      cnot_gate<7,6>(st, L);  // (0,1)
      cnot_gate<6,5>(st, L);  // (1,2)
      cnot_gate<5,4>(st, L);  // (2,3)
      cnot_gate<4,3>(st, L);  // (3,4)
      cnot_gate<3,2>(st, L);  // (4,5)
      cnot_gate<2,1>(st, L);  // (5,6)
      cnot_gate<1,0>(st, L);  // (6,7)
      cnot_gate<0,7>(st, L);  // (7,0)
    }

    #define CONVB(PH, PL, i) conv_block<PH, PL>(st, L, \
        s_rz[3*(i)][0],   s_rz[3*(i)][1],   \
        s_rz[3*(i)+1][0], s_rz[3*(i)+1][1], \
        s_rz[3*(i)+2][0], s_rz[3*(i)+2][1], \
        s_ry[2*(i)][0],   s_ry[2*(i)][1],   \
        s_ry[2*(i)+1][0], s_ry[2*(i)+1][1])
    CONVB(6, 7, 0);
    CONVB(4, 5, 1);
    CONVB(2, 3, 2);
    CONVB(0, 1, 3);

    u3_gate<6>(st, s_u3[0], L);
    u3_gate<4>(st, s_u3[1], L);
    u3_gate<2>(st, s_u3[2], L);
    u3_gate<0>(st, s_u3[3], L);

    CONVB(4, 6, 4);
    CONVB(0, 2, 5);
    CONVB(2, 4, 6);
    #undef CONVB

    u3_gate<4>(st, s_u3[4], L);
    u3_gate<0>(st, s_u3[5], L);

    // expval_z on wire 3 (bit 4 -> lane bit 2) and wire 7 (bit 0 -> reg bit 0)
    float s3 = 0.f, s7 = 0.f;
    #pragma unroll
    for (int r = 0; r < NREG; ++r) {
      float p = st.re[r]*st.re[r] + st.im[r]*st.im[r];
      s3 += p;
      s7 += (r & 1) ? -p : p;
    }
    if ((L >> 2) & 1) s3 = -s3;
    s3 += lxor<1>(s3);  s7 += lxor<1>(s7);
    s3 += lxor<2>(s3);  s7 += lxor<2>(s7);
    s3 += lxor<4>(s3);  s7 += lxor<4>(s7);
    s3 += lxor<8>(s3);  s7 += lxor<8>(s7);
    s3 += lxor<16>(s3); s7 += lxor<16>(s7);
    s3 += lxor<32>(s3); s7 += lxor<32>(s7);

    // MLP head
    float y = s_b2[0];
    #pragma unroll
    for (int j = 0; j < 10; ++j) {
      float h = tanhf(fmaf(s3, s_w1[2*j], fmaf(s7, s_w1[2*j+1], s_b1[j])));
      y = fmaf(h, s_w2[j], y);
    }
    float res = 1.f / (1.f + expf(-y));
    if (L == 0) out[g] = res;
  }
}

extern "C" void kernel_launch(void* const* d_in, const int* in_sizes, int n_in,
                              void* d_out, int out_size, void* d_ws, size_t ws_size,
                              hipStream_t stream) {
  const float* theta = (const float*)d_in[0];
  const float* phi   = (const float*)d_in[1];
  const float* rz_a  = (const float*)d_in[2];
  const float* ry_a  = (const float*)d_in[3];
  const float* u3_p  = (const float*)d_in[4];
  const float* w1    = (const float*)d_in[5];
  const float* b1    = (const float*)d_in[6];
  const float* w2    = (const float*)d_in[7];
  const float* b2    = (const float*)d_in[8];
  float* out = (float*)d_out;
  const int B = in_sizes[0];
  const int threads = 256;
  const int blocks = (B * 64 + threads - 1) / threads;
  hipLaunchKernelGGL(qcnn_kernel, dim3(blocks), dim3(threads), 0, stream,
                     theta, phi, rz_a, ry_a, u3_p, w1, b1, w2, b2, out, B);
}

// Round 12
// 31.919 us; speedup vs baseline: 1.1806x; 1.1806x over previous
//
#include <hip/hip_runtime.h>
#include <math.h>

// Batched 8-qubit state-vector sim. fp32 in / fp32 out.
// Base: R10 (PASSED, 35.7us; 32-lane/element layout - R11's 64-lane regressed).
// This round: state as packed float2 (re,im) per amplitude so gate math lowers
// to v_pk_mul_f32/v_pk_fma_f32 (full-rate packed FP32, gfx90a+). Exchanges and
// CNOT selects unchanged (R10-validated DPP quad_perm / ds_swizzle).
// NOTE: popcount-fused RZ(phi) is FORBIDDEN - reproducibly wrong (R1/R7/R9,
// exact err 8.789e-2); explicit per-wire RZ only.
// Layout: one batch element per 32-lane group (2 per wave64).
//   amplitude index a = L*8 + r, L = lane&31 (5 lane bits), r in [0,8) (3 reg bits)
//   wire w -> bit p = 7-w: p<3 register bit, p>=3 lane bit (p-3)

constexpr int NREG = 8;

typedef float v2f __attribute__((ext_vector_type(2)));

__device__ __forceinline__ v2f vfma(v2f a, v2f b, v2f c) {
  return __builtin_elementwise_fma(a, b, c);
}
__device__ __forceinline__ v2f splat(float x) { return (v2f){x, x}; }

template<int MASK>
__device__ __forceinline__ float lxor(float x) {
  int xi = __float_as_int(x);
  int r;
  if constexpr (MASK == 1)      r = __builtin_amdgcn_mov_dpp(xi, 0xB1, 0xF, 0xF, true); // quad_perm [1,0,3,2]
  else if constexpr (MASK == 2) r = __builtin_amdgcn_mov_dpp(xi, 0x4E, 0xF, 0xF, true); // quad_perm [2,3,0,1]
  else                          r = __builtin_amdgcn_ds_swizzle(xi, (MASK << 10) | 0x1F); // xor within 32 lanes
  return __int_as_float(r);
}

template<int MASK>
__device__ __forceinline__ v2f lxor2(v2f v) {
  v2f r;
  r.x = lxor<MASK>(v.x);
  r.y = lxor<MASK>(v.y);
  return r;
}

struct State {
  v2f a[NREG];  // a[r] = (re, im)
};

// RY(theta): [[c,-s],[s,c]] on bit position P  (real matrix: re/im identical math)
template<int P>
__device__ __forceinline__ void ry_gate(State& st, float c, float s, int L) {
  if constexpr (P <= 2) {
    constexpr int m = 1 << P;
    #pragma unroll
    for (int r0 = 0; r0 < NREG; ++r0) {
      if (r0 & m) continue;
      const int r1 = r0 | m;
      v2f a0 = st.a[r0], a1 = st.a[r1];
      st.a[r0] = vfma(splat(-s), a1, splat(c) * a0);
      st.a[r1] = vfma(splat( s), a0, splat(c) * a1);
    }
  } else {
    constexpr int m = 1 << (P - 3);
    float ss = ((L >> (P - 3)) & 1) ? s : -s;
    #pragma unroll
    for (int r = 0; r < NREG; ++r) {
      v2f b = lxor2<m>(st.a[r]);
      st.a[r] = vfma(splat(ss), b, splat(c) * st.a[r]);
    }
  }
}

// RZ(t): diag(e^{-it/2}, e^{+it/2}); cz=cos(t/2), sz=sin(t/2)
// amp *= (cz + i*bsign*sz):  (re,im) = cz*(re,im) + (-sg,sg)*(im,re)
template<int P>
__device__ __forceinline__ void rz_gate(State& st, float cz, float sz, int L) {
  if constexpr (P <= 2) {
    #pragma unroll
    for (int r = 0; r < NREG; ++r) {
      float sg = ((r >> P) & 1) ? sz : -sz;
      v2f v = st.a[r];
      st.a[r] = vfma((v2f){-sg, sg}, v.yx, splat(cz) * v);
    }
  } else {
    float sg = ((L >> (P - 3)) & 1) ? sz : -sz;
    #pragma unroll
    for (int r = 0; r < NREG; ++r) {
      v2f v = st.a[r];
      st.a[r] = vfma((v2f){-sg, sg}, v.yx, splat(cz) * v);
    }
  }
}

template<int PC, int PT>
__device__ __forceinline__ void cnot_gate(State& st, int L) {
  if constexpr (PT <= 2) {
    constexpr int mt = 1 << PT;
    if constexpr (PC <= 2) {
      constexpr int mc = 1 << PC;
      #pragma unroll
      for (int r0 = 0; r0 < NREG; ++r0) {
        if (!(r0 & mc) || (r0 & mt)) continue;
        const int r1 = r0 | mt;
        v2f t = st.a[r0]; st.a[r0] = st.a[r1]; st.a[r1] = t;
      }
    } else {
      bool cb = (L >> (PC - 3)) & 1;
      #pragma unroll
      for (int r0 = 0; r0 < NREG; ++r0) {
        if (r0 & mt) continue;
        const int r1 = r0 | mt;
        v2f a0 = st.a[r0], a1 = st.a[r1];
        st.a[r0] = cb ? a1 : a0;
        st.a[r1] = cb ? a0 : a1;
      }
    }
  } else {
    constexpr int mt = 1 << (PT - 3);
    if constexpr (PC <= 2) {
      constexpr int mc = 1 << PC;
      #pragma unroll
      for (int r = 0; r < NREG; ++r) {
        if (!(r & mc)) continue;
        st.a[r] = lxor2<mt>(st.a[r]);
      }
    } else {
      bool cb = (L >> (PC - 3)) & 1;
      #pragma unroll
      for (int r = 0; r < NREG; ++r) {
        v2f b = lxor2<mt>(st.a[r]);
        st.a[r] = cb ? b : st.a[r];
      }
    }
  }
}

// complex mul-acc: t += (ur + i*ui) * v   [v packed (re,im)]
__device__ __forceinline__ v2f cmac(v2f t, float ur, float ui, v2f v) {
  t = vfma(splat(ur), v, t);
  t = vfma((v2f){-ui, ui}, v.yx, t);
  return t;
}

// general complex 2x2 gate; u = {00r,00i,01r,01i,10r,10i,11r,11i} (LDS)
template<int P>
__device__ __forceinline__ void u3_gate(State& st, const float* u, int L) {
  float u00r=u[0],u00i=u[1],u01r=u[2],u01i=u[3],u10r=u[4],u10i=u[5],u11r=u[6],u11i=u[7];
  if constexpr (P <= 2) {
    constexpr int m = 1 << P;
    #pragma unroll
    for (int r0 = 0; r0 < NREG; ++r0) {
      if (r0 & m) continue;
      const int r1 = r0 | m;
      v2f a0 = st.a[r0], a1 = st.a[r1];
      v2f t0 = splat(u00r) * a0;
      t0 = vfma((v2f){-u00i, u00i}, a0.yx, t0);
      t0 = cmac(t0, u01r, u01i, a1);
      v2f t1 = splat(u10r) * a0;
      t1 = vfma((v2f){-u10i, u10i}, a0.yx, t1);
      t1 = cmac(t1, u11r, u11i, a1);
      st.a[r0] = t0;
      st.a[r1] = t1;
    }
  } else {
    constexpr int m = 1 << (P - 3);
    bool b = (L >> (P - 3)) & 1;
    float xr = b ? u11r : u00r, xi = b ? u11i : u00i;
    float yr = b ? u10r : u01r, yi = b ? u10i : u01i;
    #pragma unroll
    for (int r = 0; r < NREG; ++r) {
      v2f p = lxor2<m>(st.a[r]);
      v2f v = st.a[r];
      v2f t = splat(xr) * v;
      t = vfma((v2f){-xi, xi}, v.yx, t);
      t = cmac(t, yr, yi, p);
      st.a[r] = t;
    }
  }
}

// rz(hi); cnot(hi,lo); rz(lo); ry(hi); cnot(lo,hi); ry(hi); cnot(hi,lo); rz(lo)
template<int PH, int PL>
__device__ __forceinline__ void conv_block(State& st, int L,
    float crza,float srza, float crzb,float srzb, float crzc,float srzc,
    float crya,float srya, float cryb,float sryb) {
  rz_gate<PH>(st, crza, srza, L);
  cnot_gate<PH, PL>(st, L);
  rz_gate<PL>(st, crzb, srzb, L);
  ry_gate<PH>(st, crya, srya, L);
  cnot_gate<PL, PH>(st, L);
  ry_gate<PH>(st, cryb, sryb, L);
  cnot_gate<PH, PL>(st, L);
  rz_gate<PL>(st, crzc, srzc, L);
}

__global__ __launch_bounds__(256, 4) void qcnn_kernel(
    const float* __restrict__ theta, const float* __restrict__ phi,
    const float* __restrict__ rz_a, const float* __restrict__ ry_a,
    const float* __restrict__ u3_p,
    const float* __restrict__ w1, const float* __restrict__ b1,
    const float* __restrict__ w2, const float* __restrict__ b2,
    float* __restrict__ out, int B) {
  __shared__ float s_rz[21][2];   // (cos, sin) of half-angle
  __shared__ float s_ry[14][2];
  __shared__ float s_u3[6][8];
  __shared__ float s_w1[20];
  __shared__ float s_b1[10];
  __shared__ float s_w2[10];
  __shared__ float s_b2[1];

  const int tid = threadIdx.x;
  if (tid < 21) {
    float s, c; sincosf(0.5f * rz_a[tid], &s, &c);
    s_rz[tid][0] = c; s_rz[tid][1] = s;
  } else if (tid >= 32 && tid < 46) {
    int j = tid - 32;
    float s, c; sincosf(0.5f * ry_a[j], &s, &c);
    s_ry[j][0] = c; s_ry[j][1] = s;
  } else if (tid >= 64 && tid < 70) {
    int j = tid - 64;
    float t = u3_p[3*j], p = u3_p[3*j+1], l = u3_p[3*j+2];
    float st_, ct, sp, cp, sl, cl;
    sincosf(0.5f*t, &st_, &ct);
    sincosf(p, &sp, &cp);
    sincosf(l, &sl, &cl);
    s_u3[j][0] = ct;       s_u3[j][1] = 0.f;
    s_u3[j][2] = -cl*st_;  s_u3[j][3] = -sl*st_;
    s_u3[j][4] = cp*st_;   s_u3[j][5] = sp*st_;
    float eplr = cp*cl - sp*sl, epli = sp*cl + cp*sl;
    s_u3[j][6] = eplr*ct;  s_u3[j][7] = epli*ct;
  } else if (tid >= 96 && tid < 116) {
    s_w1[tid - 96] = w1[tid - 96];
  } else if (tid >= 128 && tid < 138) {
    s_b1[tid - 128] = b1[tid - 128];
  } else if (tid >= 160 && tid < 170) {
    s_w2[tid - 160] = w2[tid - 160];
  } else if (tid == 192) {
    s_b2[0] = b2[0];
  }
  __syncthreads();

  const int L = tid & 31;
  const int g = (blockIdx.x * blockDim.x + tid) >> 5;  // batch index
  if (g < B) {
    float th = theta[g], ph = phi[g];
    float cth, sth; sincosf(0.5f*th, &sth, &cth);
    float cph, sph; sincosf(0.5f*ph, &sph, &cph);

    State st;
    #pragma unroll
    for (int r = 0; r < NREG; ++r) st.a[r] = (v2f){0.f, 0.f};
    st.a[0].x = (L == 0) ? 1.f : 0.f;

    #pragma unroll 1
    for (int cyc = 0; cyc < 4; ++cyc) {
      // RY(theta) on wires 0..7  (P = 7-w)
      ry_gate<7>(st, cth, sth, L);
      ry_gate<6>(st, cth, sth, L);
      ry_gate<5>(st, cth, sth, L);
      ry_gate<4>(st, cth, sth, L);
      ry_gate<3>(st, cth, sth, L);
      ry_gate<2>(st, cth, sth, L);
      ry_gate<1>(st, cth, sth, L);
      ry_gate<0>(st, cth, sth, L);
      // RZ(phi) on wires 0..7, explicit
      rz_gate<7>(st, cph, sph, L);
      rz_gate<6>(st, cph, sph, L);
      rz_gate<5>(st, cph, sph, L);
      rz_gate<4>(st, cph, sph, L);
      rz_gate<3>(st, cph, sph, L);
      rz_gate<2>(st, cph, sph, L);
      rz_gate<1>(st, cph, sph, L);
      rz_gate<0>(st, cph, sph, L);
      // CNOT ring (w, w+1)
      cnot_gate<7,6>(st, L);  // (0,1)
      cnot_gate<6,5>(st, L);  // (1,2)
      cnot_gate<5,4>(st, L);  // (2,3)
      cnot_gate<4,3>(st, L);  // (3,4)
      cnot_gate<3,2>(st, L);  // (4,5)
      cnot_gate<2,1>(st, L);  // (5,6)
      cnot_gate<1,0>(st, L);  // (6,7)
      cnot_gate<0,7>(st, L);  // (7,0)
    }

    #define CONVB(PH, PL, i) conv_block<PH, PL>(st, L, \
        s_rz[3*(i)][0],   s_rz[3*(i)][1],   \
        s_rz[3*(i)+1][0], s_rz[3*(i)+1][1], \
        s_rz[3*(i)+2][0], s_rz[3*(i)+2][1], \
        s_ry[2*(i)][0],   s_ry[2*(i)][1],   \
        s_ry[2*(i)+1][0], s_ry[2*(i)+1][1])
    CONVB(6, 7, 0);
    CONVB(4, 5, 1);
    CONVB(2, 3, 2);
    CONVB(0, 1, 3);

    u3_gate<6>(st, s_u3[0], L);
    u3_gate<4>(st, s_u3[1], L);
    u3_gate<2>(st, s_u3[2], L);
    u3_gate<0>(st, s_u3[3], L);

    CONVB(4, 6, 4);
    CONVB(0, 2, 5);
    CONVB(2, 4, 6);
    #undef CONVB

    u3_gate<4>(st, s_u3[4], L);
    u3_gate<0>(st, s_u3[5], L);

    // expval_z on wire 3 (lane bit 1) and wire 7 (reg bit 0)
    float s3 = 0.f, s7 = 0.f;
    #pragma unroll
    for (int r = 0; r < NREG; ++r) {
      v2f sq = st.a[r] * st.a[r];
      float p = sq.x + sq.y;
      s3 += p;
      s7 += (r & 1) ? -p : p;
    }
    if ((L >> 1) & 1) s3 = -s3;
    s3 += lxor<1>(s3);  s7 += lxor<1>(s7);
    s3 += lxor<2>(s3);  s7 += lxor<2>(s7);
    s3 += lxor<4>(s3);  s7 += lxor<4>(s7);
    s3 += lxor<8>(s3);  s7 += lxor<8>(s7);
    s3 += lxor<16>(s3); s7 += lxor<16>(s7);

    // MLP head
    float y = s_b2[0];
    #pragma unroll
    for (int j = 0; j < 10; ++j) {
      float h = tanhf(fmaf(s3, s_w1[2*j], fmaf(s7, s_w1[2*j+1], s_b1[j])));
      y = fmaf(h, s_w2[j], y);
    }
    float res = 1.f / (1.f + expf(-y));
    if (L == 0) out[g] = res;
  }
}

extern "C" void kernel_launch(void* const* d_in, const int* in_sizes, int n_in,
                              void* d_out, int out_size, void* d_ws, size_t ws_size,
                              hipStream_t stream) {
  const float* theta = (const float*)d_in[0];
  const float* phi   = (const float*)d_in[1];
  const float* rz_a  = (const float*)d_in[2];
  const float* ry_a  = (const float*)d_in[3];
  const float* u3_p  = (const float*)d_in[4];
  const float* w1    = (const float*)d_in[5];
  const float* b1    = (const float*)d_in[6];
  const float* w2    = (const float*)d_in[7];
  const float* b2    = (const float*)d_in[8];
  float* out = (float*)d_out;
  const int B = in_sizes[0];
  const int threads = 256;
  const int blocks = (B * 32 + threads - 1) / threads;
  hipLaunchKernelGGL(qcnn_kernel, dim3(blocks), dim3(threads), 0, stream,
                     theta, phi, rz_a, ry_a, u3_p, w1, b1, w2, b2, out, B);
}